// Round 1
// baseline (2147.366 us; speedup 1.0000x reference)
//
#include <hip/hip_runtime.h>

// LSTM actor-critic forward. Strategy: episode-parallel LSTM (episode_starts
// partitions every sequence into independent chains since h,c are zeroed at
// each start), on-the-fly x-gates, f32 vector math throughout.
//
// ws layout: [0,256): counters | [256, 256+2MB): episode list (int2) |
//            fl_pi (N*64 f32)  | fl_vf (N*64 f32)   (feat, overwritten in
//            place by the LSTM hidden output "lat" — row r's feat is dead
//            after step r consumes it, so aliasing is safe)
// ws required ~= 137 MB.

#define NSEQ  256
#define TT    1024
#define NROWS (NSEQ * TT)     // 262144
#define OBS   128
#define ACTN  16
#define HH    64

__device__ __forceinline__ float frcp(float x)  { return __builtin_amdgcn_rcpf(x); }
__device__ __forceinline__ float fsigm(float x) { return frcp(1.f + __expf(-x)); }
__device__ __forceinline__ float ftanh(float x) { return 1.f - 2.f * frcp(1.f + __expf(2.f * x)); }

// ---------------------------------------------------------------- K0: zero counters
__global__ void lstm_ac_zero(int* ctrs) {
    if (threadIdx.x < 2) ctrs[threadIdx.x] = 0;
}

// ---------------------------------------------------------------- K1: episode extraction
// ep flags (0/1 float) per (seq,t). Episode = [start, next start). t=0 always a start.
__global__ void lstm_ac_episodes(const float* __restrict__ ep,
                                 int* __restrict__ ctrs, int2* __restrict__ eps) {
    __shared__ float flags[TT];
    const int s = blockIdx.x;
    for (int i = threadIdx.x; i < TT; i += blockDim.x) flags[i] = ep[(size_t)s * TT + i];
    __syncthreads();
    for (int t0 = threadIdx.x; t0 < TT; t0 += blockDim.x) {
        const bool start = (t0 == 0) || (flags[t0] > 0.5f);
        if (start) {
            int t1 = t0 + 1;
            while (t1 < TT && !(flags[t1] > 0.5f)) t1++;
            const int slot = atomicAdd(&ctrs[0], 1);
            eps[slot] = make_int2(s * TT + t0, t1 - t0);
        }
    }
}

// ---------------------------------------------------------------- K2: MLP features (one branch per launch)
// Wave-cooperative: lane j owns output feature j; W1 row j (128 f32) + W2 row j
// (64 f32) live in VGPRs; the input row is broadcast via per-wave LDS float4 reads.
__global__ __launch_bounds__(256) void lstm_ac_feat(
    const float* __restrict__ obs,
    const float* __restrict__ W1, const float* __restrict__ b1,
    const float* __restrict__ W2, const float* __restrict__ b2,
    float* __restrict__ feat) {
    __shared__ float x_lds[4][OBS];
    __shared__ float l1_lds[4][HH];
    const int tid = threadIdx.x;
    const int w = tid >> 6, j = tid & 63;

    float w1r[OBS], w2r[HH];
    {
        const float4* p1 = (const float4*)(W1 + (size_t)j * OBS);
#pragma unroll
        for (int q = 0; q < OBS / 4; q++) {
            float4 v = p1[q];
            w1r[4*q] = v.x; w1r[4*q+1] = v.y; w1r[4*q+2] = v.z; w1r[4*q+3] = v.w;
        }
        const float4* p2 = (const float4*)(W2 + (size_t)j * HH);
#pragma unroll
        for (int q = 0; q < HH / 4; q++) {
            float4 v = p2[q];
            w2r[4*q] = v.x; w2r[4*q+1] = v.y; w2r[4*q+2] = v.z; w2r[4*q+3] = v.w;
        }
    }
    const float bb1 = b1[j], bb2 = b2[j];
    const int gw = blockIdx.x * 4 + w;   // global wave id; 1024 blocks * 4 waves * 64 rows = N

    for (int rr = 0; rr < 64; ++rr) {
        const int r = gw * 64 + rr;
        // coalesced stage of the obs row into this wave's LDS strip
        x_lds[w][j]      = obs[(size_t)r * OBS + j];
        x_lds[w][HH + j] = obs[(size_t)r * OBS + HH + j];
        const float4* xv4 = (const float4*)x_lds[w];
        float sa[4] = {0.f, 0.f, 0.f, 0.f};
#pragma unroll
        for (int q = 0; q < OBS / 4; q++) {
            float4 v = xv4[q];
            sa[q & 3] += v.x * w1r[4*q] + v.y * w1r[4*q+1] + v.z * w1r[4*q+2] + v.w * w1r[4*q+3];
        }
        const float l1 = ftanh(bb1 + (sa[0] + sa[1]) + (sa[2] + sa[3]));
        l1_lds[w][j] = l1;
        const float4* lv4 = (const float4*)l1_lds[w];
        float ta[4] = {0.f, 0.f, 0.f, 0.f};
#pragma unroll
        for (int q = 0; q < HH / 4; q++) {
            float4 v = lv4[q];
            ta[q & 3] += v.x * w2r[4*q] + v.y * w2r[4*q+1] + v.z * w2r[4*q+2] + v.w * w2r[4*q+3];
        }
        feat[(size_t)r * HH + j] = ftanh(bb2 + (ta[0] + ta[1]) + (ta[2] + ta[3]));
    }
}

// ---------------------------------------------------------------- K3: episode-parallel LSTM scan
// One episode per workgroup at a time (dynamic task queue). 4 waves = gate
// blocks i,f,g,o; lane = one gate. Wih/Whh rows in VGPRs. h,c,x in LDS.
// Writes h back into the feat buffer (aliased "lat").
__global__ __launch_bounds__(256) void lstm_ac_scan(
    float* __restrict__ fl_pi, float* __restrict__ fl_vf,
    const float* __restrict__ Wih_pi, const float* __restrict__ Whh_pi,
    const float* __restrict__ bih_pi, const float* __restrict__ bhh_pi,
    const float* __restrict__ Wih_vf, const float* __restrict__ Whh_vf,
    const float* __restrict__ bih_vf, const float* __restrict__ bhh_vf,
    int* __restrict__ ctrs, const int2* __restrict__ eps) {
    __shared__ float h_lds[HH], c_lds[HH], x_lds[HH], g_lds[4 * HH];
    __shared__ int task_s;
    const int tid = threadIdx.x;
    const int w = tid >> 6, j = tid & 63;
    const int gidx = tid;                 // gate index 0..255 (i,f,g,o blocks)
    const int ep_count = ctrs[0];
    const int ntasks = 2 * ep_count;      // [0,ep_count) = pi, rest = vf

    int cur = -1;
    float wih[HH], whh[HH], bg = 0.f;
    float* fl = fl_pi;

    for (;;) {
        if (tid == 0) task_s = atomicAdd(&ctrs[1], 1);
        __syncthreads();
        const int task = task_s;
        if (task >= ntasks) break;
        const int l = (task >= ep_count) ? 1 : 0;
        if (l != cur) {                   // monotone task ids: at most one switch per block
            cur = l;
            const float* Wih = l ? Wih_vf : Wih_pi;
            const float* Whh = l ? Whh_vf : Whh_pi;
            const float* bih = l ? bih_vf : bih_pi;
            const float* bhh = l ? bhh_vf : bhh_pi;
            fl = l ? fl_vf : fl_pi;
            const float4* p1 = (const float4*)(Wih + (size_t)gidx * HH);
            const float4* p2 = (const float4*)(Whh + (size_t)gidx * HH);
#pragma unroll
            for (int q = 0; q < HH / 4; q++) {
                float4 a = p1[q];
                wih[4*q] = a.x; wih[4*q+1] = a.y; wih[4*q+2] = a.z; wih[4*q+3] = a.w;
                float4 b = p2[q];
                whh[4*q] = b.x; whh[4*q+1] = b.y; whh[4*q+2] = b.z; whh[4*q+3] = b.w;
            }
            bg = bih[gidx] + bhh[gidx];
        }
        const int2 e = eps[(task >= ep_count) ? (task - ep_count) : task];
        const int r0 = e.x, len = e.y;

        if (w == 0) { h_lds[j] = 0.f; c_lds[j] = 0.f; }
        if (w == 1 && j < 16)
            ((float4*)x_lds)[j] = ((const float4*)(fl + (size_t)r0 * HH))[j];
        __syncthreads();

        for (int t = 0; t < len; ++t) {
            // phase A: gate = bias + x.Wih_row + h.Whh_row, then nonlinearity
            float a0 = bg, a1 = 0.f, a2 = 0.f, a3 = 0.f;
            const float4* hv4 = (const float4*)h_lds;
            const float4* xv4 = (const float4*)x_lds;
#pragma unroll
            for (int q = 0; q < HH / 4; q++) {
                float4 hv = hv4[q];
                float4 xv = xv4[q];
                float p = hv.x * whh[4*q] + hv.y * whh[4*q+1] + hv.z * whh[4*q+2] + hv.w * whh[4*q+3]
                        + xv.x * wih[4*q] + xv.y * wih[4*q+1] + xv.z * wih[4*q+2] + xv.w * wih[4*q+3];
                if ((q & 3) == 0) a0 += p; else if ((q & 3) == 1) a1 += p;
                else if ((q & 3) == 2) a2 += p; else a3 += p;
            }
            const float g = (a0 + a1) + (a2 + a3);
            g_lds[gidx] = (w == 2) ? ftanh(g) : fsigm(g);   // i,f,o sigmoid; g tanh
            __syncthreads();
            // phase B: wave0 updates state + writes h; wave1 prefetches next x row
            if (w == 0) {
                float c = g_lds[HH + j] * c_lds[j] + g_lds[j] * g_lds[2 * HH + j];
                float h = g_lds[3 * HH + j] * ftanh(c);
                c_lds[j] = c;
                h_lds[j] = h;
                fl[(size_t)(r0 + t) * HH + j] = h;   // safe: this feat row already consumed
            } else if (w == 1 && j < 16 && (t + 1) < len) {
                ((float4*)x_lds)[j] = ((const float4*)(fl + (size_t)(r0 + t + 1) * HH))[j];
            }
            __syncthreads();
        }
    }
}

// ---------------------------------------------------------------- K4: policy/value heads
__global__ __launch_bounds__(256) void lstm_ac_heads(
    const float* __restrict__ lat_pi, const float* __restrict__ lat_vf,
    const int* __restrict__ action,
    const float* __restrict__ Wa, const float* __restrict__ ba,
    const float* __restrict__ Wc, const float* __restrict__ bc,
    float* __restrict__ out) {
    const int r = blockIdx.x * 256 + threadIdx.x;
    float4 lp[16];
    const float4* pp = (const float4*)(lat_pi + (size_t)r * HH);
#pragma unroll
    for (int q = 0; q < 16; q++) lp[q] = pp[q];

    float logits[ACTN];
#pragma unroll
    for (int a = 0; a < ACTN; a++) {
        const float4* wp = (const float4*)(Wa + (size_t)a * HH);   // uniform -> scalar loads
        float s0 = 0.f, s1 = 0.f, s2 = 0.f, s3 = 0.f;
#pragma unroll
        for (int q = 0; q < 16; q++) {
            float4 wv = wp[q];
            s0 += lp[q].x * wv.x; s1 += lp[q].y * wv.y;
            s2 += lp[q].z * wv.z; s3 += lp[q].w * wv.w;
        }
        logits[a] = ba[a] + (s0 + s1) + (s2 + s3);
    }
    float m = logits[0];
#pragma unroll
    for (int a = 1; a < ACTN; a++) m = fmaxf(m, logits[a]);
    float s0 = 0.f, s1 = 0.f;
#pragma unroll
    for (int a = 0; a < ACTN; a++) {
        const float e = __expf(logits[a] - m);
        s0 += e;
        s1 += e * logits[a];
    }
    const float lse = m + __logf(s0);
    const int act = action[r];
    float la = logits[0];
#pragma unroll
    for (int a = 1; a < ACTN; a++) la = (act == a) ? logits[a] : la;  // no dynamic reg indexing
    out[r] = la - lse;                       // logprob
    out[NROWS + r] = lse - s1 * frcp(s0);    // entropy = lse - E[logit]

    const float4* pv = (const float4*)(lat_vf + (size_t)r * HH);
    const float4* wc4 = (const float4*)Wc;
    float t0 = 0.f, t1 = 0.f, t2 = 0.f, t3 = 0.f;
#pragma unroll
    for (int q = 0; q < 16; q++) {
        float4 v = pv[q];
        float4 wv = wc4[q];
        t0 += v.x * wv.x; t1 += v.y * wv.y; t2 += v.z * wv.z; t3 += v.w * wv.w;
    }
    out[2 * (size_t)NROWS + r] = bc[0] + (t0 + t1) + (t2 + t3);
}

// ---------------------------------------------------------------- launch
extern "C" void kernel_launch(void* const* d_in, const int* in_sizes, int n_in,
                              void* d_out, int out_size, void* d_ws, size_t ws_size,
                              hipStream_t stream) {
    const float* obs    = (const float*)d_in[0];
    const int*   action = (const int*)d_in[1];
    const float* epst   = (const float*)d_in[2];
    // d_in[3..6] = h0/c0: all-zero by construction (episode_starts[:,0]==1 forces reset)
    const float* Wp1 = (const float*)d_in[7];
    const float* bp1 = (const float*)d_in[8];
    const float* Wp2 = (const float*)d_in[9];
    const float* bp2 = (const float*)d_in[10];
    const float* Wv1 = (const float*)d_in[11];
    const float* bv1 = (const float*)d_in[12];
    const float* Wv2 = (const float*)d_in[13];
    const float* bv2 = (const float*)d_in[14];
    const float* Wih_pi = (const float*)d_in[15];
    const float* Whh_pi = (const float*)d_in[16];
    const float* bih_pi = (const float*)d_in[17];
    const float* bhh_pi = (const float*)d_in[18];
    const float* Wih_vf = (const float*)d_in[19];
    const float* Whh_vf = (const float*)d_in[20];
    const float* bih_vf = (const float*)d_in[21];
    const float* bhh_vf = (const float*)d_in[22];
    const float* Wa = (const float*)d_in[23];
    const float* ba = (const float*)d_in[24];
    const float* Wc = (const float*)d_in[25];
    const float* bc = (const float*)d_in[26];
    float* out = (float*)d_out;

    char* ws = (char*)d_ws;
    int*  ctrs = (int*)ws;
    int2* eps  = (int2*)(ws + 256);
    float* fl_pi = (float*)(ws + 256 + (size_t)NROWS * sizeof(int2));
    float* fl_vf = fl_pi + (size_t)NROWS * HH;

    lstm_ac_zero<<<1, 64, 0, stream>>>(ctrs);
    lstm_ac_episodes<<<NSEQ, 256, 0, stream>>>(epst, ctrs, eps);
    lstm_ac_feat<<<NROWS / 256, 256, 0, stream>>>(obs, Wp1, bp1, Wp2, bp2, fl_pi);
    lstm_ac_feat<<<NROWS / 256, 256, 0, stream>>>(obs, Wv1, bv1, Wv2, bv2, fl_vf);
    lstm_ac_scan<<<2048, 256, 0, stream>>>(fl_pi, fl_vf,
                                           Wih_pi, Whh_pi, bih_pi, bhh_pi,
                                           Wih_vf, Whh_vf, bih_vf, bhh_vf,
                                           ctrs, eps);
    lstm_ac_heads<<<NROWS / 256, 256, 0, stream>>>(fl_pi, fl_vf, action,
                                                   Wa, ba, Wc, bc, out);
}

// Round 3
// 1906.928 us; speedup vs baseline: 1.1261x; 1.1261x over previous
//
#include <hip/hip_runtime.h>

// LSTM actor-critic forward, round 2 (resubmit — round-2 bench never ran).
// - Episode-parallel LSTM (episode_starts partition sequences; h,c reset at
//   each start, and t=0 is always a start so h0/c0 inputs are irrelevant).
// - Device counting-sort of episodes by length (descending), scan processes
//   groups of 4 near-equal-length episodes per 512-thread block.
// - k-split gate layout: lane = (gate, k-half) -> 32+32 weight floats per
//   lane, keeps VGPR <= 128 (register-resident weights; round-1 spilled at
//   VGPR_Count=84 -> scratch-bound).
//
// ws layout: ctrs[8] | hist[1024] | offs[1024] | raw eps (2MB) | sorted eps
//            (2MB) | fl_pi (67MB) | fl_vf (67MB).  ~138.5 MB total.
// fl_* hold the MLP features and are overwritten in place by the LSTM hidden
// output (row r's feat is dead once step r consumed it).

#define NSEQ  256
#define TT    1024
#define NROWS (NSEQ * TT)     // 262144
#define OBS   128
#define ACTN  16
#define HH    64
#define MAXEP NROWS

__device__ __forceinline__ float frcp(float x)  { return __builtin_amdgcn_rcpf(x); }
__device__ __forceinline__ float fsigm(float x) { return frcp(1.f + __expf(-x)); }
__device__ __forceinline__ float ftanh(float x) { return 1.f - 2.f * frcp(1.f + __expf(2.f * x)); }

// ---------------------------------------------------------------- K0: zero counters + histogram
__global__ void lstm_ac_zero(int* ctrs, int* hist) {
    const int t = threadIdx.x;
    hist[t] = 0;
    if (t < 8) ctrs[t] = 0;
}

// ---------------------------------------------------------------- K1: episode extraction + length histogram
__global__ void lstm_ac_episodes(const float* __restrict__ ep,
                                 int* __restrict__ ctrs, int* __restrict__ hist,
                                 int2* __restrict__ raw) {
    __shared__ float flags[TT];
    const int s = blockIdx.x;
    for (int i = threadIdx.x; i < TT; i += blockDim.x) flags[i] = ep[(size_t)s * TT + i];
    __syncthreads();
    for (int t0 = threadIdx.x; t0 < TT; t0 += blockDim.x) {
        const bool start = (t0 == 0) || (flags[t0] > 0.5f);
        if (start) {
            int t1 = t0 + 1;
            while (t1 < TT && !(flags[t1] > 0.5f)) t1++;
            const int len = t1 - t0;
            const int slot = atomicAdd(&ctrs[0], 1);
            raw[slot] = make_int2(s * TT + t0, len);
            atomicAdd(&hist[len - 1], 1);
        }
    }
}

// ---------------------------------------------------------------- K2: suffix prefix-sum (descending-length offsets)
__global__ void lstm_ac_prefix(const int* __restrict__ hist, int* __restrict__ offs) {
    __shared__ int a[1024];
    const int tid = threadIdx.x;
    const int h0 = hist[tid];
    a[tid] = h0;
    __syncthreads();
    for (int s = 1; s < 1024; s <<= 1) {
        const int v = (tid + s < 1024) ? a[tid + s] : 0;
        __syncthreads();
        a[tid] += v;
        __syncthreads();
    }
    offs[tid] = a[tid] - h0;   // sum of counts of strictly longer episodes
}

// ---------------------------------------------------------------- K3: scatter into length-sorted order
__global__ void lstm_ac_scatter(const int* __restrict__ ctrs, const int2* __restrict__ raw,
                                int* __restrict__ offs, int2* __restrict__ sorted) {
    const int i = blockIdx.x * 256 + threadIdx.x;
    if (i < ctrs[0]) {
        const int2 e = raw[i];
        const int slot = atomicAdd(&offs[e.y - 1], 1);
        sorted[slot] = e;
    }
}

// ---------------------------------------------------------------- K4: MLP features (one branch per launch)
// Lane j owns output feature j; W1 row j (128 f32) + W2 row j (64 f32) in
// VGPRs (launch_bounds(256,2) -> cap 256 regs, no spill).
__global__ __launch_bounds__(256, 2) void lstm_ac_feat(
    const float* __restrict__ obs,
    const float* __restrict__ W1, const float* __restrict__ b1,
    const float* __restrict__ W2, const float* __restrict__ b2,
    float* __restrict__ feat) {
    __shared__ float x_lds[4][OBS];
    __shared__ float l1_lds[4][HH];
    const int tid = threadIdx.x;
    const int w = tid >> 6, j = tid & 63;

    float w1r[OBS], w2r[HH];
    {
        const float4* p1 = (const float4*)(W1 + (size_t)j * OBS);
#pragma unroll
        for (int q = 0; q < OBS / 4; q++) {
            float4 v = p1[q];
            w1r[4*q] = v.x; w1r[4*q+1] = v.y; w1r[4*q+2] = v.z; w1r[4*q+3] = v.w;
        }
        const float4* p2 = (const float4*)(W2 + (size_t)j * HH);
#pragma unroll
        for (int q = 0; q < HH / 4; q++) {
            float4 v = p2[q];
            w2r[4*q] = v.x; w2r[4*q+1] = v.y; w2r[4*q+2] = v.z; w2r[4*q+3] = v.w;
        }
    }
    const float bb1 = b1[j], bb2 = b2[j];
    const int gw = blockIdx.x * 4 + w;       // 2048 blocks * 4 waves

    for (int rr = 0; rr < 32; ++rr) {
        const int r = gw * 32 + rr;
        x_lds[w][j]      = obs[(size_t)r * OBS + j];
        x_lds[w][HH + j] = obs[(size_t)r * OBS + HH + j];
        const float4* xv4 = (const float4*)x_lds[w];
        float sa[4] = {0.f, 0.f, 0.f, 0.f};
#pragma unroll
        for (int q = 0; q < OBS / 4; q++) {
            float4 v = xv4[q];
            sa[q & 3] += v.x * w1r[4*q] + v.y * w1r[4*q+1] + v.z * w1r[4*q+2] + v.w * w1r[4*q+3];
        }
        const float l1 = ftanh(bb1 + (sa[0] + sa[1]) + (sa[2] + sa[3]));
        l1_lds[w][j] = l1;
        const float4* lv4 = (const float4*)l1_lds[w];
        float ta[4] = {0.f, 0.f, 0.f, 0.f};
#pragma unroll
        for (int q = 0; q < HH / 4; q++) {
            float4 v = lv4[q];
            ta[q & 3] += v.x * w2r[4*q] + v.y * w2r[4*q+1] + v.z * w2r[4*q+2] + v.w * w2r[4*q+3];
        }
        feat[(size_t)r * HH + j] = ftanh(bb2 + (ta[0] + ta[1]) + (ta[2] + ta[3]));
    }
}

// ---------------------------------------------------------------- K5: batched episode-parallel LSTM scan
// 512 threads = 8 waves. Gate layout: lane l of wave w handles gate
// g = 32w + (l>>1), k-half kh = l&1 (32 of the 64 h/x elements). Weight
// footprint per lane: 32+32 f32 -> register resident at <=128 VGPR.
// 4 episodes (near-equal length, from the sorted list) per block per group;
// one barrier pair serves all 4. Phase B: waves 0-3 update h/c of episode w
// (c in registers), waves 4-7 ds_write the prefetched next x row.
__global__ __launch_bounds__(512, 3) void lstm_ac_scan(
    float* __restrict__ fl_pi, float* __restrict__ fl_vf,
    const float* __restrict__ Wih_pi, const float* __restrict__ Whh_pi,
    const float* __restrict__ bih_pi, const float* __restrict__ bhh_pi,
    const float* __restrict__ Wih_vf, const float* __restrict__ Whh_vf,
    const float* __restrict__ bih_vf, const float* __restrict__ bhh_vf,
    int* __restrict__ ctrs, const int2* __restrict__ sorted) {
    __shared__ float x_lds[4][HH];
    __shared__ float h_lds[4][HH];
    __shared__ float g_lds[4][4 * HH];
    __shared__ int task_s;

    const int tid = threadIdx.x;
    const int w   = tid >> 6;               // wave 0..7
    const int l   = tid & 63;
    const int g   = (w << 5) + (l >> 1);    // gate 0..255 (type = w>>1)
    const int kh  = l & 1;
    const int kbase = kh * 32;
    const bool upd = (w < 4);
    const int b_me = upd ? w : (w - 4);     // episode slot this wave serves in phase B
    const int j = l;
    const bool is_tanh_gate = ((w >> 1) == 2);

    const int cnt = ctrs[0];
    const int G = (cnt + 3) >> 2;
    const int ntasks = 2 * G;

    int cur = -1;
    float wih[32], whh[32];
    float bg = 0.f;
    float* fl = fl_pi;
    float c_reg = 0.f;

    for (;;) {
        __syncthreads();
        if (tid == 0) task_s = atomicAdd(&ctrs[1], 1);
        __syncthreads();
        const int task = task_s;
        if (task >= ntasks) break;
        const int lstm = (task >= G) ? 1 : 0;
        const int gq = lstm ? (task - G) : task;
        if (lstm != cur) {                  // per-block task ids increase: <=1 switch
            cur = lstm;
            const float* Wih = lstm ? Wih_vf : Wih_pi;
            const float* Whh = lstm ? Whh_vf : Whh_pi;
            const float* bih = lstm ? bih_vf : bih_pi;
            const float* bhh = lstm ? bhh_vf : bhh_pi;
            fl = lstm ? fl_vf : fl_pi;
            const float4* p1 = (const float4*)(Wih + (size_t)g * HH + kbase);
            const float4* p2 = (const float4*)(Whh + (size_t)g * HH + kbase);
#pragma unroll
            for (int q = 0; q < 8; q++) {
                float4 a = p1[q];
                wih[4*q+0] = a.x; wih[4*q+1] = a.y; wih[4*q+2] = a.z; wih[4*q+3] = a.w;
                float4 b = p2[q];
                whh[4*q+0] = b.x; whh[4*q+1] = b.y; whh[4*q+2] = b.z; whh[4*q+3] = b.w;
            }
            bg = (kh == 0) ? (bih[g] + bhh[g]) : 0.f;
        }

        int r0[4], ln[4];
#pragma unroll
        for (int s = 0; s < 4; s++) {
            const int idx = gq * 4 + s;
            if (idx < cnt) { const int2 e = sorted[idx]; r0[s] = e.x; ln[s] = e.y; }
            else { r0[s] = 0; ln[s] = 0; }
        }
        const int maxlen = ln[0];           // descending sort -> slot 0 is longest

        if (upd) { h_lds[b_me][j] = 0.f; c_reg = 0.f; }
        else if (ln[b_me] > 0) x_lds[b_me][j] = fl[(size_t)r0[b_me] * HH + j];
        __syncthreads();

        for (int t = 0; t < maxlen; ++t) {
            // issue next x-row load early; consumed in phase B (latency hides
            // under the gate FMAs)
            float xnext = 0.f;
            if (!upd) {
                const int tn = t + 1;
                const int rr = (tn < ln[b_me]) ? (r0[b_me] + tn) : r0[b_me];
                xnext = fl[(size_t)rr * HH + j];
            }
            // phase A: gates for all active episodes (uniform predicates)
#pragma unroll
            for (int b = 0; b < 4; b++) {
                if (t < ln[b]) {
                    const float4* xv = (const float4*)&x_lds[b][kbase];
                    const float4* hv = (const float4*)&h_lds[b][kbase];
                    float a0 = bg, a1 = 0.f, a2 = 0.f, a3 = 0.f;
#pragma unroll
                    for (int q = 0; q < 8; q++) {
                        const float4 x4 = xv[q];
                        const float4 h4 = hv[q];
                        a0 += x4.x * wih[4*q+0] + h4.x * whh[4*q+0];
                        a1 += x4.y * wih[4*q+1] + h4.y * whh[4*q+1];
                        a2 += x4.z * wih[4*q+2] + h4.z * whh[4*q+2];
                        a3 += x4.w * wih[4*q+3] + h4.w * whh[4*q+3];
                    }
                    float part = (a0 + a1) + (a2 + a3);
                    part += __shfl_xor(part, 1, 64);         // combine k-halves (DPP)
                    g_lds[b][g] = is_tanh_gate ? ftanh(part) : fsigm(part);
                }
            }
            __syncthreads();
            // phase B
            if (upd) {
                if (t < ln[b_me]) {
                    const float gi = g_lds[b_me][j];
                    const float gf = g_lds[b_me][HH + j];
                    const float gg = g_lds[b_me][2 * HH + j];
                    const float go = g_lds[b_me][3 * HH + j];
                    c_reg = gf * c_reg + gi * gg;
                    const float h = go * ftanh(c_reg);
                    h_lds[b_me][j] = h;
                    fl[(size_t)(r0[b_me] + t) * HH + j] = h;  // feat row already consumed
                }
            } else {
                if (t + 1 < ln[b_me]) x_lds[b_me][j] = xnext;
            }
            __syncthreads();
        }
    }
}

// ---------------------------------------------------------------- K6: policy/value heads
__global__ __launch_bounds__(256) void lstm_ac_heads(
    const float* __restrict__ lat_pi, const float* __restrict__ lat_vf,
    const int* __restrict__ action,
    const float* __restrict__ Wa, const float* __restrict__ ba,
    const float* __restrict__ Wc, const float* __restrict__ bc,
    float* __restrict__ out) {
    const int r = blockIdx.x * 256 + threadIdx.x;
    float4 lp[16];
    const float4* pp = (const float4*)(lat_pi + (size_t)r * HH);
#pragma unroll
    for (int q = 0; q < 16; q++) lp[q] = pp[q];

    float logits[ACTN];
#pragma unroll
    for (int a = 0; a < ACTN; a++) {
        const float4* wp = (const float4*)(Wa + (size_t)a * HH);
        float s0 = 0.f, s1 = 0.f, s2 = 0.f, s3 = 0.f;
#pragma unroll
        for (int q = 0; q < 16; q++) {
            const float4 wv = wp[q];
            s0 += lp[q].x * wv.x; s1 += lp[q].y * wv.y;
            s2 += lp[q].z * wv.z; s3 += lp[q].w * wv.w;
        }
        logits[a] = ba[a] + (s0 + s1) + (s2 + s3);
    }
    float m = logits[0];
#pragma unroll
    for (int a = 1; a < ACTN; a++) m = fmaxf(m, logits[a]);
    float s0 = 0.f, s1 = 0.f;
#pragma unroll
    for (int a = 0; a < ACTN; a++) {
        const float e = __expf(logits[a] - m);
        s0 += e;
        s1 += e * logits[a];
    }
    const float lse = m + __logf(s0);
    const int act = action[r];
    float la = logits[0];
#pragma unroll
    for (int a = 1; a < ACTN; a++) la = (act == a) ? logits[a] : la;
    out[r] = la - lse;
    out[NROWS + r] = lse - s1 * frcp(s0);

    const float4* pv = (const float4*)(lat_vf + (size_t)r * HH);
    const float4* wc4 = (const float4*)Wc;
    float t0 = 0.f, t1 = 0.f, t2 = 0.f, t3 = 0.f;
#pragma unroll
    for (int q = 0; q < 16; q++) {
        const float4 v = pv[q];
        const float4 wv = wc4[q];
        t0 += v.x * wv.x; t1 += v.y * wv.y; t2 += v.z * wv.z; t3 += v.w * wv.w;
    }
    out[2 * (size_t)NROWS + r] = bc[0] + (t0 + t1) + (t2 + t3);
}

// ---------------------------------------------------------------- launch
extern "C" void kernel_launch(void* const* d_in, const int* in_sizes, int n_in,
                              void* d_out, int out_size, void* d_ws, size_t ws_size,
                              hipStream_t stream) {
    const float* obs    = (const float*)d_in[0];
    const int*   action = (const int*)d_in[1];
    const float* epst   = (const float*)d_in[2];
    const float* Wp1 = (const float*)d_in[7];
    const float* bp1 = (const float*)d_in[8];
    const float* Wp2 = (const float*)d_in[9];
    const float* bp2 = (const float*)d_in[10];
    const float* Wv1 = (const float*)d_in[11];
    const float* bv1 = (const float*)d_in[12];
    const float* Wv2 = (const float*)d_in[13];
    const float* bv2 = (const float*)d_in[14];
    const float* Wih_pi = (const float*)d_in[15];
    const float* Whh_pi = (const float*)d_in[16];
    const float* bih_pi = (const float*)d_in[17];
    const float* bhh_pi = (const float*)d_in[18];
    const float* Wih_vf = (const float*)d_in[19];
    const float* Whh_vf = (const float*)d_in[20];
    const float* bih_vf = (const float*)d_in[21];
    const float* bhh_vf = (const float*)d_in[22];
    const float* Wa = (const float*)d_in[23];
    const float* ba = (const float*)d_in[24];
    const float* Wc = (const float*)d_in[25];
    const float* bc = (const float*)d_in[26];
    float* out = (float*)d_out;

    char* ws = (char*)d_ws;
    int*  ctrs   = (int*)ws;
    int*  hist   = (int*)(ws + 32);
    int*  offs   = (int*)(ws + 32 + 4096);
    int2* raw    = (int2*)(ws + 32 + 8192);
    int2* sorted = raw + MAXEP;
    float* fl_pi = (float*)((char*)(sorted + MAXEP));
    float* fl_vf = fl_pi + (size_t)NROWS * HH;

    lstm_ac_zero<<<1, 1024, 0, stream>>>(ctrs, hist);
    lstm_ac_episodes<<<NSEQ, 256, 0, stream>>>(epst, ctrs, hist, raw);
    lstm_ac_feat<<<2048, 256, 0, stream>>>(obs, Wp1, bp1, Wp2, bp2, fl_pi);
    lstm_ac_feat<<<2048, 256, 0, stream>>>(obs, Wv1, bv1, Wv2, bv2, fl_vf);
    lstm_ac_prefix<<<1, 1024, 0, stream>>>(hist, offs);
    lstm_ac_scatter<<<1024, 256, 0, stream>>>(ctrs, raw, offs, sorted);
    lstm_ac_scan<<<1024, 512, 0, stream>>>(fl_pi, fl_vf,
                                           Wih_pi, Whh_pi, bih_pi, bhh_pi,
                                           Wih_vf, Whh_vf, bih_vf, bhh_vf,
                                           ctrs, sorted);
    lstm_ac_heads<<<NROWS / 256, 256, 0, stream>>>(fl_pi, fl_vf, action,
                                                   Wa, ba, Wc, bc, out);
}

// Round 4
// 1797.116 us; speedup vs baseline: 1.1949x; 1.0611x over previous
//
#include <hip/hip_runtime.h>

// LSTM actor-critic forward, round 3.
// Round-2 lesson: __launch_bounds__ 2nd arg is only a MIN waves/EU — the RA
// still targeted 8 waves/SIMD (VGPR_Count=60 < the 64 weight floats) and
// spilled the weights to scratch. Fix: amdgpu_waves_per_eu(min,MAX) clamps
// the occupancy target so the register budget fits the weights.
// - Episode-parallel LSTM (episode_starts partition sequences; t=0 always a
//   start so h0/c0 inputs are irrelevant).
// - Device counting-sort of episodes by length (descending); groups of 4
//   near-equal-length episodes per 512-thread block; longest group grabbed
//   first (bounds the serial tail).
// - k-split gates: lane = (gate, k-half) -> 32+32 weight floats per lane,
//   register-resident under the 128-VGPR budget.
//
// ws layout: ctrs[8] | hist[1024] | offs[1024] | raw eps (2MB) | sorted eps
//            (2MB) | fl_pi (67MB) | fl_vf (67MB).
// fl_* hold MLP features, overwritten in place by LSTM hidden output (row r's
// feat is dead once step r consumed it).

#define NSEQ  256
#define TT    1024
#define NROWS (NSEQ * TT)     // 262144
#define OBS   128
#define ACTN  16
#define HH    64
#define MAXEP NROWS

__device__ __forceinline__ float frcp(float x)  { return __builtin_amdgcn_rcpf(x); }
__device__ __forceinline__ float fsigm(float x) { return frcp(1.f + __expf(-x)); }
__device__ __forceinline__ float ftanh(float x) { return 1.f - 2.f * frcp(1.f + __expf(2.f * x)); }

// ---------------------------------------------------------------- K0: zero counters + histogram
__global__ void lstm_ac_zero(int* ctrs, int* hist) {
    const int t = threadIdx.x;
    hist[t] = 0;
    if (t < 8) ctrs[t] = 0;
}

// ---------------------------------------------------------------- K1: episode extraction + length histogram
__global__ void lstm_ac_episodes(const float* __restrict__ ep,
                                 int* __restrict__ ctrs, int* __restrict__ hist,
                                 int2* __restrict__ raw) {
    __shared__ float flags[TT];
    const int s = blockIdx.x;
    for (int i = threadIdx.x; i < TT; i += blockDim.x) flags[i] = ep[(size_t)s * TT + i];
    __syncthreads();
    for (int t0 = threadIdx.x; t0 < TT; t0 += blockDim.x) {
        const bool start = (t0 == 0) || (flags[t0] > 0.5f);
        if (start) {
            int t1 = t0 + 1;
            while (t1 < TT && !(flags[t1] > 0.5f)) t1++;
            const int len = t1 - t0;
            const int slot = atomicAdd(&ctrs[0], 1);
            raw[slot] = make_int2(s * TT + t0, len);
            atomicAdd(&hist[len - 1], 1);
        }
    }
}

// ---------------------------------------------------------------- K2: suffix prefix-sum (descending-length offsets)
__global__ void lstm_ac_prefix(const int* __restrict__ hist, int* __restrict__ offs) {
    __shared__ int a[1024];
    const int tid = threadIdx.x;
    const int h0 = hist[tid];
    a[tid] = h0;
    __syncthreads();
    for (int s = 1; s < 1024; s <<= 1) {
        const int v = (tid + s < 1024) ? a[tid + s] : 0;
        __syncthreads();
        a[tid] += v;
        __syncthreads();
    }
    offs[tid] = a[tid] - h0;   // count of strictly longer episodes
}

// ---------------------------------------------------------------- K3: scatter into length-sorted order
__global__ void lstm_ac_scatter(const int* __restrict__ ctrs, const int2* __restrict__ raw,
                                int* __restrict__ offs, int2* __restrict__ sorted) {
    const int i = blockIdx.x * 256 + threadIdx.x;
    if (i < ctrs[0]) {
        const int2 e = raw[i];
        const int slot = atomicAdd(&offs[e.y - 1], 1);
        sorted[slot] = e;
    }
}

// ---------------------------------------------------------------- K4: MLP features (both branches, one launch)
// blocks [0,2048) -> pi branch, [2048,4096) -> vf. Lane j owns output feature
// j; W1 row j (128 f32) + W2 row j (64 f32) in VGPRs. waves_per_eu(2,2)
// grants a 256-VGPR budget so the 192 weight floats stay resident.
__global__ __launch_bounds__(256) __attribute__((amdgpu_waves_per_eu(2, 2)))
void lstm_ac_feat(
    const float* __restrict__ obs,
    const float* __restrict__ Wp1, const float* __restrict__ bp1,
    const float* __restrict__ Wp2, const float* __restrict__ bp2,
    const float* __restrict__ Wv1, const float* __restrict__ bv1,
    const float* __restrict__ Wv2, const float* __restrict__ bv2,
    float* __restrict__ fl_pi, float* __restrict__ fl_vf) {
    __shared__ float x_lds[4][OBS];
    __shared__ float l1_lds[4][HH];
    const int tid = threadIdx.x;
    const int w = tid >> 6, j = tid & 63;
    const int half = blockIdx.x >> 11;            // 0 = pi, 1 = vf
    const float* W1 = half ? Wv1 : Wp1;
    const float* b1 = half ? bv1 : bp1;
    const float* W2 = half ? Wv2 : Wp2;
    const float* b2 = half ? bv2 : bp2;
    float* feat = half ? fl_vf : fl_pi;

    float w1r[OBS], w2r[HH];
    {
        const float4* p1 = (const float4*)(W1 + (size_t)j * OBS);
#pragma unroll
        for (int q = 0; q < OBS / 4; q++) {
            float4 v = p1[q];
            w1r[4*q] = v.x; w1r[4*q+1] = v.y; w1r[4*q+2] = v.z; w1r[4*q+3] = v.w;
        }
        const float4* p2 = (const float4*)(W2 + (size_t)j * HH);
#pragma unroll
        for (int q = 0; q < HH / 4; q++) {
            float4 v = p2[q];
            w2r[4*q] = v.x; w2r[4*q+1] = v.y; w2r[4*q+2] = v.z; w2r[4*q+3] = v.w;
        }
    }
    const float bb1 = b1[j], bb2 = b2[j];
    const int gw = (blockIdx.x & 2047) * 4 + w;   // 2048 blocks * 4 waves per branch

    // register prefetch of the first row (T14 issue-early pattern)
    float xa = obs[(size_t)(gw * 32) * OBS + j];
    float xb = obs[(size_t)(gw * 32) * OBS + HH + j];
    for (int rr = 0; rr < 32; ++rr) {
        const int r = gw * 32 + rr;
        x_lds[w][j]      = xa;
        x_lds[w][HH + j] = xb;
        if (rr + 1 < 32) {                        // issue next row's load now
            xa = obs[(size_t)(r + 1) * OBS + j];
            xb = obs[(size_t)(r + 1) * OBS + HH + j];
        }
        const float4* xv4 = (const float4*)x_lds[w];
        float sa[4] = {0.f, 0.f, 0.f, 0.f};
#pragma unroll
        for (int q = 0; q < OBS / 4; q++) {
            float4 v = xv4[q];
            sa[q & 3] += v.x * w1r[4*q] + v.y * w1r[4*q+1] + v.z * w1r[4*q+2] + v.w * w1r[4*q+3];
        }
        const float l1 = ftanh(bb1 + (sa[0] + sa[1]) + (sa[2] + sa[3]));
        l1_lds[w][j] = l1;
        const float4* lv4 = (const float4*)l1_lds[w];
        float ta[4] = {0.f, 0.f, 0.f, 0.f};
#pragma unroll
        for (int q = 0; q < HH / 4; q++) {
            float4 v = lv4[q];
            ta[q & 3] += v.x * w2r[4*q] + v.y * w2r[4*q+1] + v.z * w2r[4*q+2] + v.w * w2r[4*q+3];
        }
        feat[(size_t)r * HH + j] = ftanh(bb2 + (ta[0] + ta[1]) + (ta[2] + ta[3]));
    }
}

// ---------------------------------------------------------------- K5: batched episode-parallel LSTM scan
// 512 threads = 8 waves. Gate layout: lane l of wave w handles gate
// g = 32w + (l>>1), k-half kh = l&1. Weight footprint 64 f32/lane —
// register-resident under waves_per_eu(4,4)'s 128-VGPR budget.
// 4 episodes (near-equal length) per block-group; phase B: waves 0-3 update
// h/c of episode w (c in registers), waves 4-7 stage the next x row.
__global__ __launch_bounds__(512) __attribute__((amdgpu_waves_per_eu(4, 4)))
void lstm_ac_scan(
    float* __restrict__ fl_pi, float* __restrict__ fl_vf,
    const float* __restrict__ Wih_pi, const float* __restrict__ Whh_pi,
    const float* __restrict__ bih_pi, const float* __restrict__ bhh_pi,
    const float* __restrict__ Wih_vf, const float* __restrict__ Whh_vf,
    const float* __restrict__ bih_vf, const float* __restrict__ bhh_vf,
    int* __restrict__ ctrs, const int2* __restrict__ sorted) {
    __shared__ float x_lds[4][HH];
    __shared__ float h_lds[4][HH];
    __shared__ float g_lds[4][4 * HH];
    __shared__ int task_s;

    const int tid = threadIdx.x;
    const int w   = tid >> 6;               // wave 0..7
    const int l   = tid & 63;
    const int g   = (w << 5) + (l >> 1);    // gate 0..255 (i,f,g,o blocks)
    const int kh  = l & 1;
    const int kbase = kh * 32;
    const bool upd = (w < 4);
    const int b_me = upd ? w : (w - 4);     // episode slot this wave serves in phase B
    const int j = l;
    const bool is_tanh_gate = ((w >> 1) == 2);

    const int cnt = ctrs[0];
    const int G = (cnt + 3) >> 2;
    const int ntasks = 2 * G;

    int cur = -1;
    float wih[32], whh[32];
    float bg = 0.f;
    float* fl = fl_pi;
    float c_reg = 0.f;

    for (;;) {
        __syncthreads();
        if (tid == 0) task_s = atomicAdd(&ctrs[1], 1);
        __syncthreads();
        const int task = task_s;
        if (task >= ntasks) break;
        const int lstm = (task >= G) ? 1 : 0;
        const int gq = lstm ? (task - G) : task;
        if (lstm != cur) {                  // task ids increase per block: <=1 switch
            cur = lstm;
            const float* Wih = lstm ? Wih_vf : Wih_pi;
            const float* Whh = lstm ? Whh_vf : Whh_pi;
            const float* bih = lstm ? bih_vf : bih_pi;
            const float* bhh = lstm ? bhh_vf : bhh_pi;
            fl = lstm ? fl_vf : fl_pi;
            const float4* p1 = (const float4*)(Wih + (size_t)g * HH + kbase);
            const float4* p2 = (const float4*)(Whh + (size_t)g * HH + kbase);
#pragma unroll
            for (int q = 0; q < 8; q++) {
                float4 a = p1[q];
                wih[4*q+0] = a.x; wih[4*q+1] = a.y; wih[4*q+2] = a.z; wih[4*q+3] = a.w;
                float4 b = p2[q];
                whh[4*q+0] = b.x; whh[4*q+1] = b.y; whh[4*q+2] = b.z; whh[4*q+3] = b.w;
            }
            bg = (kh == 0) ? (bih[g] + bhh[g]) : 0.f;
        }

        // named scalars (no runtime-indexed locals -> no scratch)
        const int base = gq * 4;
        int2 e;
        e = (base + 0 < cnt) ? sorted[base + 0] : make_int2(0, 0); const int r00 = e.x, ln0 = e.y;
        e = (base + 1 < cnt) ? sorted[base + 1] : make_int2(0, 0); const int r01 = e.x, ln1 = e.y;
        e = (base + 2 < cnt) ? sorted[base + 2] : make_int2(0, 0); const int r02 = e.x, ln2 = e.y;
        e = (base + 3 < cnt) ? sorted[base + 3] : make_int2(0, 0); const int r03 = e.x, ln3 = e.y;
        const int r0_me = (b_me == 0) ? r00 : (b_me == 1) ? r01 : (b_me == 2) ? r02 : r03;
        const int ln_me = (b_me == 0) ? ln0 : (b_me == 1) ? ln1 : (b_me == 2) ? ln2 : ln3;
        const int maxlen = ln0;             // descending sort -> slot 0 longest

        if (upd) { h_lds[b_me][j] = 0.f; c_reg = 0.f; }
        else if (ln_me > 0) x_lds[b_me][j] = fl[(size_t)r0_me * HH + j];
        __syncthreads();

        for (int t = 0; t < maxlen; ++t) {
            // issue next x-row load early; consumed in phase B (latency hides
            // under the gate FMAs)
            float xnext = 0.f;
            if (!upd) {
                const int tn = t + 1;
                const int rr = (tn < ln_me) ? (r0_me + tn) : r0_me;
                xnext = fl[(size_t)rr * HH + j];
            }
            // phase A: gates for all active episodes (wave-uniform predicates)
#define GATE_B(B, LNB)                                                          \
            if (t < LNB) {                                                      \
                const float4* xv = (const float4*)&x_lds[B][kbase];             \
                const float4* hv = (const float4*)&h_lds[B][kbase];             \
                float a0 = bg, a1 = 0.f, a2 = 0.f, a3 = 0.f;                    \
                _Pragma("unroll")                                               \
                for (int q = 0; q < 8; q++) {                                   \
                    const float4 x4 = xv[q];                                    \
                    const float4 h4 = hv[q];                                    \
                    a0 += x4.x * wih[4*q+0] + h4.x * whh[4*q+0];                \
                    a1 += x4.y * wih[4*q+1] + h4.y * whh[4*q+1];                \
                    a2 += x4.z * wih[4*q+2] + h4.z * whh[4*q+2];                \
                    a3 += x4.w * wih[4*q+3] + h4.w * whh[4*q+3];                \
                }                                                               \
                float part = (a0 + a1) + (a2 + a3);                             \
                part += __shfl_xor(part, 1, 64);                                \
                g_lds[B][g] = is_tanh_gate ? ftanh(part) : fsigm(part);         \
            }
            GATE_B(0, ln0)
            GATE_B(1, ln1)
            GATE_B(2, ln2)
            GATE_B(3, ln3)
#undef GATE_B
            __syncthreads();
            // phase B
            if (upd) {
                if (t < ln_me) {
                    const float gi = g_lds[b_me][j];
                    const float gf = g_lds[b_me][HH + j];
                    const float gg = g_lds[b_me][2 * HH + j];
                    const float go = g_lds[b_me][3 * HH + j];
                    c_reg = gf * c_reg + gi * gg;
                    const float h = go * ftanh(c_reg);
                    h_lds[b_me][j] = h;
                    fl[(size_t)(r0_me + t) * HH + j] = h;  // feat row already consumed
                }
            } else {
                if (t + 1 < ln_me) x_lds[b_me][j] = xnext;
            }
            __syncthreads();
        }
    }
}

// ---------------------------------------------------------------- K6: policy/value heads
__global__ __launch_bounds__(256) __attribute__((amdgpu_waves_per_eu(4, 4)))
void lstm_ac_heads(
    const float* __restrict__ lat_pi, const float* __restrict__ lat_vf,
    const int* __restrict__ action,
    const float* __restrict__ Wa, const float* __restrict__ ba,
    const float* __restrict__ Wc, const float* __restrict__ bc,
    float* __restrict__ out) {
    const int r = blockIdx.x * 256 + threadIdx.x;
    float4 lp[16];
    const float4* pp = (const float4*)(lat_pi + (size_t)r * HH);
#pragma unroll
    for (int q = 0; q < 16; q++) lp[q] = pp[q];

    float logits[ACTN];
#pragma unroll
    for (int a = 0; a < ACTN; a++) {
        const float4* wp = (const float4*)(Wa + (size_t)a * HH);  // uniform -> s_loads
        float s0 = 0.f, s1 = 0.f, s2 = 0.f, s3 = 0.f;
#pragma unroll
        for (int q = 0; q < 16; q++) {
            const float4 wv = wp[q];
            s0 += lp[q].x * wv.x; s1 += lp[q].y * wv.y;
            s2 += lp[q].z * wv.z; s3 += lp[q].w * wv.w;
        }
        logits[a] = ba[a] + (s0 + s1) + (s2 + s3);
    }
    float m = logits[0];
#pragma unroll
    for (int a = 1; a < ACTN; a++) m = fmaxf(m, logits[a]);
    float s0 = 0.f, s1 = 0.f;
#pragma unroll
    for (int a = 0; a < ACTN; a++) {
        const float e = __expf(logits[a] - m);
        s0 += e;
        s1 += e * logits[a];
    }
    const float lse = m + __logf(s0);
    const int act = action[r];
    float la = logits[0];
#pragma unroll
    for (int a = 1; a < ACTN; a++) la = (act == a) ? logits[a] : la;
    out[r] = la - lse;
    out[NROWS + r] = lse - s1 * frcp(s0);

    const float4* pv = (const float4*)(lat_vf + (size_t)r * HH);
    const float4* wc4 = (const float4*)Wc;
    float t0 = 0.f, t1 = 0.f, t2 = 0.f, t3 = 0.f;
#pragma unroll
    for (int q = 0; q < 16; q++) {
        const float4 v = pv[q];
        const float4 wv = wc4[q];
        t0 += v.x * wv.x; t1 += v.y * wv.y; t2 += v.z * wv.z; t3 += v.w * wv.w;
    }
    out[2 * (size_t)NROWS + r] = bc[0] + (t0 + t1) + (t2 + t3);
}

// ---------------------------------------------------------------- launch
extern "C" void kernel_launch(void* const* d_in, const int* in_sizes, int n_in,
                              void* d_out, int out_size, void* d_ws, size_t ws_size,
                              hipStream_t stream) {
    const float* obs    = (const float*)d_in[0];
    const int*   action = (const int*)d_in[1];
    const float* epst   = (const float*)d_in[2];
    const float* Wp1 = (const float*)d_in[7];
    const float* bp1 = (const float*)d_in[8];
    const float* Wp2 = (const float*)d_in[9];
    const float* bp2 = (const float*)d_in[10];
    const float* Wv1 = (const float*)d_in[11];
    const float* bv1 = (const float*)d_in[12];
    const float* Wv2 = (const float*)d_in[13];
    const float* bv2 = (const float*)d_in[14];
    const float* Wih_pi = (const float*)d_in[15];
    const float* Whh_pi = (const float*)d_in[16];
    const float* bih_pi = (const float*)d_in[17];
    const float* bhh_pi = (const float*)d_in[18];
    const float* Wih_vf = (const float*)d_in[19];
    const float* Whh_vf = (const float*)d_in[20];
    const float* bih_vf = (const float*)d_in[21];
    const float* bhh_vf = (const float*)d_in[22];
    const float* Wa = (const float*)d_in[23];
    const float* ba = (const float*)d_in[24];
    const float* Wc = (const float*)d_in[25];
    const float* bc = (const float*)d_in[26];
    float* out = (float*)d_out;

    char* ws = (char*)d_ws;
    int*  ctrs   = (int*)ws;
    int*  hist   = (int*)(ws + 32);
    int*  offs   = (int*)(ws + 32 + 4096);
    int2* raw    = (int2*)(ws + 32 + 8192);
    int2* sorted = raw + MAXEP;
    float* fl_pi = (float*)((char*)(sorted + MAXEP));
    float* fl_vf = fl_pi + (size_t)NROWS * HH;

    lstm_ac_zero<<<1, 1024, 0, stream>>>(ctrs, hist);
    lstm_ac_episodes<<<NSEQ, 256, 0, stream>>>(epst, ctrs, hist, raw);
    lstm_ac_feat<<<4096, 256, 0, stream>>>(obs, Wp1, bp1, Wp2, bp2,
                                           Wv1, bv1, Wv2, bv2, fl_pi, fl_vf);
    lstm_ac_prefix<<<1, 1024, 0, stream>>>(hist, offs);
    lstm_ac_scatter<<<1024, 256, 0, stream>>>(ctrs, raw, offs, sorted);
    lstm_ac_scan<<<1024, 512, 0, stream>>>(fl_pi, fl_vf,
                                           Wih_pi, Whh_pi, bih_pi, bhh_pi,
                                           Wih_vf, Whh_vf, bih_vf, bhh_vf,
                                           ctrs, sorted);
    lstm_ac_heads<<<NROWS / 256, 256, 0, stream>>>(fl_pi, fl_vf, action,
                                                   Wa, ba, Wc, bc, out);
}

// Round 5
// 1749.716 us; speedup vs baseline: 1.2273x; 1.0271x over previous
//
#include <hip/hip_runtime.h>

// LSTM actor-critic forward, round 4.
// Round-3 lesson: amdgpu_waves_per_eu(4,4) was ignored (VGPR stayed 60) —
// the RA targets max-achievable occupancy and REMATERIALIZES the invariant
// weight loads instead of spilling (they're const __restrict__ -> "free").
// This round forces the register budget mechanically: 56 KB static LDS per
// block caps occupancy at 2 blocks/CU (160/56), i.e. 4 waves/SIMD for the
// 512-thread scan -> 128-VGPR budget -> the 64 weight floats stay resident.
// Same trick for feat (56 KB, 256-thread -> 2 waves/SIMD -> 256-VGPR budget
// for its 192 weight floats).
//
// Scan is critical-path bound: ~430-step longest episode x per-step latency.
// Register-resident weights cut the per-step latency; batching/sort keep the
// queue (bulk) part overlapped with the tail.

#define NSEQ  256
#define TT    1024
#define NROWS (NSEQ * TT)     // 262144
#define OBS   128
#define ACTN  16
#define HH    64
#define MAXEP NROWS

__device__ __forceinline__ float frcp(float x)  { return __builtin_amdgcn_rcpf(x); }
__device__ __forceinline__ float fsigm(float x) { return frcp(1.f + __expf(-x)); }
__device__ __forceinline__ float ftanh(float x) { return 1.f - 2.f * frcp(1.f + __expf(2.f * x)); }

// ---------------------------------------------------------------- K0: zero counters + histogram
__global__ void lstm_ac_zero(int* ctrs, int* hist) {
    const int t = threadIdx.x;
    hist[t] = 0;
    if (t < 8) ctrs[t] = 0;
}

// ---------------------------------------------------------------- K1: episode extraction + length histogram
__global__ void lstm_ac_episodes(const float* __restrict__ ep,
                                 int* __restrict__ ctrs, int* __restrict__ hist,
                                 int2* __restrict__ raw) {
    __shared__ float flags[TT];
    const int s = blockIdx.x;
    for (int i = threadIdx.x; i < TT; i += blockDim.x) flags[i] = ep[(size_t)s * TT + i];
    __syncthreads();
    for (int t0 = threadIdx.x; t0 < TT; t0 += blockDim.x) {
        const bool start = (t0 == 0) || (flags[t0] > 0.5f);
        if (start) {
            int t1 = t0 + 1;
            while (t1 < TT && !(flags[t1] > 0.5f)) t1++;
            const int len = t1 - t0;
            const int slot = atomicAdd(&ctrs[0], 1);
            raw[slot] = make_int2(s * TT + t0, len);
            atomicAdd(&hist[len - 1], 1);
        }
    }
}

// ---------------------------------------------------------------- K2: suffix prefix-sum (descending-length offsets)
__global__ void lstm_ac_prefix(const int* __restrict__ hist, int* __restrict__ offs) {
    __shared__ int a[1024];
    const int tid = threadIdx.x;
    const int h0 = hist[tid];
    a[tid] = h0;
    __syncthreads();
    for (int s = 1; s < 1024; s <<= 1) {
        const int v = (tid + s < 1024) ? a[tid + s] : 0;
        __syncthreads();
        a[tid] += v;
        __syncthreads();
    }
    offs[tid] = a[tid] - h0;   // count of strictly longer episodes
}

// ---------------------------------------------------------------- K3: scatter into length-sorted order
__global__ void lstm_ac_scatter(const int* __restrict__ ctrs, const int2* __restrict__ raw,
                                int* __restrict__ offs, int2* __restrict__ sorted) {
    const int i = blockIdx.x * 256 + threadIdx.x;
    if (i < ctrs[0]) {
        const int2 e = raw[i];
        const int slot = atomicAdd(&offs[e.y - 1], 1);
        sorted[slot] = e;
    }
}

// ---------------------------------------------------------------- K4: MLP features (both branches, one launch)
// blocks [0,2048) -> pi, [2048,4096) -> vf. Lane j owns output feature j;
// W1 row j (128 f32) + W2 row j (64 f32) in VGPRs. 56 KB LDS -> 2 blocks/CU
// -> 2 waves/SIMD RA target -> 256-VGPR budget (weights resident, no remat).
__global__ __launch_bounds__(256)
void lstm_ac_feat(
    const float* __restrict__ obs,
    const float* __restrict__ Wp1, const float* __restrict__ bp1,
    const float* __restrict__ Wp2, const float* __restrict__ bp2,
    const float* __restrict__ Wv1, const float* __restrict__ bv1,
    const float* __restrict__ Wv2, const float* __restrict__ bv2,
    float* __restrict__ fl_pi, float* __restrict__ fl_vf) {
    __shared__ float lds_pool[14336];             // 56 KB occupancy clamp
    float (*x_lds)[OBS] = (float (*)[OBS])(lds_pool);        // [4][128]
    float (*l1_lds)[HH] = (float (*)[HH])(lds_pool + 4 * OBS); // [4][64]
    const int tid = threadIdx.x;
    const int w = tid >> 6, j = tid & 63;
    const int half = blockIdx.x >> 11;            // 0 = pi, 1 = vf
    const float* W1 = half ? Wv1 : Wp1;
    const float* b1 = half ? bv1 : bp1;
    const float* W2 = half ? Wv2 : Wp2;
    const float* b2 = half ? bv2 : bp2;
    float* feat = half ? fl_vf : fl_pi;

    float w1r[OBS], w2r[HH];
    {
        const float4* p1 = (const float4*)(W1 + (size_t)j * OBS);
#pragma unroll
        for (int q = 0; q < OBS / 4; q++) {
            float4 v = p1[q];
            w1r[4*q] = v.x; w1r[4*q+1] = v.y; w1r[4*q+2] = v.z; w1r[4*q+3] = v.w;
        }
        const float4* p2 = (const float4*)(W2 + (size_t)j * HH);
#pragma unroll
        for (int q = 0; q < HH / 4; q++) {
            float4 v = p2[q];
            w2r[4*q] = v.x; w2r[4*q+1] = v.y; w2r[4*q+2] = v.z; w2r[4*q+3] = v.w;
        }
    }
    const float bb1 = b1[j], bb2 = b2[j];
    const int gw = (blockIdx.x & 2047) * 4 + w;   // 2048 blocks * 4 waves per branch

    // register prefetch of the first row (issue-early pattern)
    float xa = obs[(size_t)(gw * 32) * OBS + j];
    float xb = obs[(size_t)(gw * 32) * OBS + HH + j];
    for (int rr = 0; rr < 32; ++rr) {
        const int r = gw * 32 + rr;
        x_lds[w][j]      = xa;
        x_lds[w][HH + j] = xb;
        if (rr + 1 < 32) {                        // issue next row's load now
            xa = obs[(size_t)(r + 1) * OBS + j];
            xb = obs[(size_t)(r + 1) * OBS + HH + j];
        }
        const float4* xv4 = (const float4*)x_lds[w];
        float sa[4] = {0.f, 0.f, 0.f, 0.f};
#pragma unroll
        for (int q = 0; q < OBS / 4; q++) {
            float4 v = xv4[q];
            sa[q & 3] += v.x * w1r[4*q] + v.y * w1r[4*q+1] + v.z * w1r[4*q+2] + v.w * w1r[4*q+3];
        }
        const float l1 = ftanh(bb1 + (sa[0] + sa[1]) + (sa[2] + sa[3]));
        l1_lds[w][j] = l1;
        const float4* lv4 = (const float4*)l1_lds[w];
        float ta[4] = {0.f, 0.f, 0.f, 0.f};
#pragma unroll
        for (int q = 0; q < HH / 4; q++) {
            float4 v = lv4[q];
            ta[q & 3] += v.x * w2r[4*q] + v.y * w2r[4*q+1] + v.z * w2r[4*q+2] + v.w * w2r[4*q+3];
        }
        feat[(size_t)r * HH + j] = ftanh(bb2 + (ta[0] + ta[1]) + (ta[2] + ta[3]));
    }
}

// ---------------------------------------------------------------- K5: batched episode-parallel LSTM scan
// 512 threads = 8 waves; lane l of wave w: gate g = 32w + (l>>1), k-half
// kh = l&1 -> 32+32 weight floats per lane. 56 KB LDS -> 2 blocks/CU ->
// 4 waves/SIMD RA target -> 128-VGPR budget -> weights register-resident.
__global__ __launch_bounds__(512)
void lstm_ac_scan(
    float* __restrict__ fl_pi, float* __restrict__ fl_vf,
    const float* __restrict__ Wih_pi, const float* __restrict__ Whh_pi,
    const float* __restrict__ bih_pi, const float* __restrict__ bhh_pi,
    const float* __restrict__ Wih_vf, const float* __restrict__ Whh_vf,
    const float* __restrict__ bih_vf, const float* __restrict__ bhh_vf,
    int* __restrict__ ctrs, const int2* __restrict__ sorted) {
    __shared__ float lds_pool[14336];             // 56 KB occupancy clamp
    float (*x_lds)[HH]     = (float (*)[HH])(lds_pool);          // [4][64]
    float (*h_lds)[HH]     = (float (*)[HH])(lds_pool + 256);    // [4][64]
    float (*g_lds)[4 * HH] = (float (*)[4 * HH])(lds_pool + 512);// [4][256]
    __shared__ int task_s;

    const int tid = threadIdx.x;
    const int w   = tid >> 6;               // wave 0..7
    const int l   = tid & 63;
    const int g   = (w << 5) + (l >> 1);    // gate 0..255 (i,f,g,o blocks)
    const int kh  = l & 1;
    const int kbase = kh * 32;
    const bool upd = (w < 4);
    const int b_me = upd ? w : (w - 4);     // episode slot this wave serves in phase B
    const int j = l;
    const bool is_tanh_gate = ((w >> 1) == 2);

    const int cnt = ctrs[0];
    const int G = (cnt + 3) >> 2;
    const int ntasks = 2 * G;

    int cur = -1;
    float wih[32], whh[32];
    float bg = 0.f;
    float* fl = fl_pi;
    float c_reg = 0.f;

    for (;;) {
        __syncthreads();
        if (tid == 0) task_s = atomicAdd(&ctrs[1], 1);
        __syncthreads();
        const int task = task_s;
        if (task >= ntasks) break;
        const int lstm = (task >= G) ? 1 : 0;
        const int gq = lstm ? (task - G) : task;
        if (lstm != cur) {                  // task ids increase per block: <=1 switch
            cur = lstm;
            const float* Wih = lstm ? Wih_vf : Wih_pi;
            const float* Whh = lstm ? Whh_vf : Whh_pi;
            const float* bih = lstm ? bih_vf : bih_pi;
            const float* bhh = lstm ? bhh_vf : bhh_pi;
            fl = lstm ? fl_vf : fl_pi;
            const float4* p1 = (const float4*)(Wih + (size_t)g * HH + kbase);
            const float4* p2 = (const float4*)(Whh + (size_t)g * HH + kbase);
#pragma unroll
            for (int q = 0; q < 8; q++) {
                float4 a = p1[q];
                wih[4*q+0] = a.x; wih[4*q+1] = a.y; wih[4*q+2] = a.z; wih[4*q+3] = a.w;
                float4 b = p2[q];
                whh[4*q+0] = b.x; whh[4*q+1] = b.y; whh[4*q+2] = b.z; whh[4*q+3] = b.w;
            }
            bg = (kh == 0) ? (bih[g] + bhh[g]) : 0.f;
        }

        // named scalars (no runtime-indexed locals -> no scratch)
        const int base = gq * 4;
        int2 e;
        e = (base + 0 < cnt) ? sorted[base + 0] : make_int2(0, 0); const int r00 = e.x, ln0 = e.y;
        e = (base + 1 < cnt) ? sorted[base + 1] : make_int2(0, 0); const int r01 = e.x, ln1 = e.y;
        e = (base + 2 < cnt) ? sorted[base + 2] : make_int2(0, 0); const int r02 = e.x, ln2 = e.y;
        e = (base + 3 < cnt) ? sorted[base + 3] : make_int2(0, 0); const int r03 = e.x, ln3 = e.y;
        const int r0_me = (b_me == 0) ? r00 : (b_me == 1) ? r01 : (b_me == 2) ? r02 : r03;
        const int ln_me = (b_me == 0) ? ln0 : (b_me == 1) ? ln1 : (b_me == 2) ? ln2 : ln3;
        const int maxlen = ln0;             // descending sort -> slot 0 longest

        if (upd) { h_lds[b_me][j] = 0.f; c_reg = 0.f; }
        else if (ln_me > 0) x_lds[b_me][j] = fl[(size_t)r0_me * HH + j];
        __syncthreads();

        for (int t = 0; t < maxlen; ++t) {
            // issue next x-row load early; consumed in phase B (latency hides
            // under the gate FMAs)
            float xnext = 0.f;
            if (!upd) {
                const int tn = t + 1;
                const int rr = (tn < ln_me) ? (r0_me + tn) : r0_me;
                xnext = fl[(size_t)rr * HH + j];
            }
            // phase A: gates for all active episodes (wave-uniform predicates)
#define GATE_B(B, LNB)                                                          \
            if (t < LNB) {                                                      \
                const float4* xv = (const float4*)&x_lds[B][kbase];             \
                const float4* hv = (const float4*)&h_lds[B][kbase];             \
                float a0 = bg, a1 = 0.f, a2 = 0.f, a3 = 0.f;                    \
                _Pragma("unroll")                                               \
                for (int q = 0; q < 8; q++) {                                   \
                    const float4 x4 = xv[q];                                    \
                    const float4 h4 = hv[q];                                    \
                    a0 += x4.x * wih[4*q+0] + h4.x * whh[4*q+0];                \
                    a1 += x4.y * wih[4*q+1] + h4.y * whh[4*q+1];                \
                    a2 += x4.z * wih[4*q+2] + h4.z * whh[4*q+2];                \
                    a3 += x4.w * wih[4*q+3] + h4.w * whh[4*q+3];                \
                }                                                               \
                float part = (a0 + a1) + (a2 + a3);                             \
                part += __shfl_xor(part, 1, 64);                                \
                g_lds[B][g] = is_tanh_gate ? ftanh(part) : fsigm(part);         \
            }
            GATE_B(0, ln0)
            GATE_B(1, ln1)
            GATE_B(2, ln2)
            GATE_B(3, ln3)
#undef GATE_B
            __syncthreads();
            // phase B
            if (upd) {
                if (t < ln_me) {
                    const float gi = g_lds[b_me][j];
                    const float gf = g_lds[b_me][HH + j];
                    const float gg = g_lds[b_me][2 * HH + j];
                    const float go = g_lds[b_me][3 * HH + j];
                    c_reg = gf * c_reg + gi * gg;
                    const float h = go * ftanh(c_reg);
                    h_lds[b_me][j] = h;
                    fl[(size_t)(r0_me + t) * HH + j] = h;  // feat row already consumed
                }
            } else {
                if (t + 1 < ln_me) x_lds[b_me][j] = xnext;
            }
            __syncthreads();
        }
    }
}

// ---------------------------------------------------------------- K6: policy/value heads
__global__ __launch_bounds__(256)
void lstm_ac_heads(
    const float* __restrict__ lat_pi, const float* __restrict__ lat_vf,
    const int* __restrict__ action,
    const float* __restrict__ Wa, const float* __restrict__ ba,
    const float* __restrict__ Wc, const float* __restrict__ bc,
    float* __restrict__ out) {
    const int r = blockIdx.x * 256 + threadIdx.x;
    float4 lp[16];
    const float4* pp = (const float4*)(lat_pi + (size_t)r * HH);
#pragma unroll
    for (int q = 0; q < 16; q++) lp[q] = pp[q];

    float logits[ACTN];
#pragma unroll
    for (int a = 0; a < ACTN; a++) {
        const float4* wp = (const float4*)(Wa + (size_t)a * HH);  // uniform -> s_loads
        float s0 = 0.f, s1 = 0.f, s2 = 0.f, s3 = 0.f;
#pragma unroll
        for (int q = 0; q < 16; q++) {
            const float4 wv = wp[q];
            s0 += lp[q].x * wv.x; s1 += lp[q].y * wv.y;
            s2 += lp[q].z * wv.z; s3 += lp[q].w * wv.w;
        }
        logits[a] = ba[a] + (s0 + s1) + (s2 + s3);
    }
    float m = logits[0];
#pragma unroll
    for (int a = 1; a < ACTN; a++) m = fmaxf(m, logits[a]);
    float s0 = 0.f, s1 = 0.f;
#pragma unroll
    for (int a = 0; a < ACTN; a++) {
        const float e = __expf(logits[a] - m);
        s0 += e;
        s1 += e * logits[a];
    }
    const float lse = m + __logf(s0);
    const int act = action[r];
    float la = logits[0];
#pragma unroll
    for (int a = 1; a < ACTN; a++) la = (act == a) ? logits[a] : la;
    out[r] = la - lse;
    out[NROWS + r] = lse - s1 * frcp(s0);

    const float4* pv = (const float4*)(lat_vf + (size_t)r * HH);
    const float4* wc4 = (const float4*)Wc;
    float t0 = 0.f, t1 = 0.f, t2 = 0.f, t3 = 0.f;
#pragma unroll
    for (int q = 0; q < 16; q++) {
        const float4 v = pv[q];
        const float4 wv = wc4[q];
        t0 += v.x * wv.x; t1 += v.y * wv.y; t2 += v.z * wv.z; t3 += v.w * wv.w;
    }
    out[2 * (size_t)NROWS + r] = bc[0] + (t0 + t1) + (t2 + t3);
}

// ---------------------------------------------------------------- launch
extern "C" void kernel_launch(void* const* d_in, const int* in_sizes, int n_in,
                              void* d_out, int out_size, void* d_ws, size_t ws_size,
                              hipStream_t stream) {
    const float* obs    = (const float*)d_in[0];
    const int*   action = (const int*)d_in[1];
    const float* epst   = (const float*)d_in[2];
    const float* Wp1 = (const float*)d_in[7];
    const float* bp1 = (const float*)d_in[8];
    const float* Wp2 = (const float*)d_in[9];
    const float* bp2 = (const float*)d_in[10];
    const float* Wv1 = (const float*)d_in[11];
    const float* bv1 = (const float*)d_in[12];
    const float* Wv2 = (const float*)d_in[13];
    const float* bv2 = (const float*)d_in[14];
    const float* Wih_pi = (const float*)d_in[15];
    const float* Whh_pi = (const float*)d_in[16];
    const float* bih_pi = (const float*)d_in[17];
    const float* bhh_pi = (const float*)d_in[18];
    const float* Wih_vf = (const float*)d_in[19];
    const float* Whh_vf = (const float*)d_in[20];
    const float* bih_vf = (const float*)d_in[21];
    const float* bhh_vf = (const float*)d_in[22];
    const float* Wa = (const float*)d_in[23];
    const float* ba = (const float*)d_in[24];
    const float* Wc = (const float*)d_in[25];
    const float* bc = (const float*)d_in[26];
    float* out = (float*)d_out;

    char* ws = (char*)d_ws;
    int*  ctrs   = (int*)ws;
    int*  hist   = (int*)(ws + 32);
    int*  offs   = (int*)(ws + 32 + 4096);
    int2* raw    = (int2*)(ws + 32 + 8192);
    int2* sorted = raw + MAXEP;
    float* fl_pi = (float*)((char*)(sorted + MAXEP));
    float* fl_vf = fl_pi + (size_t)NROWS * HH;

    lstm_ac_zero<<<1, 1024, 0, stream>>>(ctrs, hist);
    lstm_ac_episodes<<<NSEQ, 256, 0, stream>>>(epst, ctrs, hist, raw);
    lstm_ac_feat<<<4096, 256, 0, stream>>>(obs, Wp1, bp1, Wp2, bp2,
                                           Wv1, bv1, Wv2, bv2, fl_pi, fl_vf);
    lstm_ac_prefix<<<1, 1024, 0, stream>>>(hist, offs);
    lstm_ac_scatter<<<1024, 256, 0, stream>>>(ctrs, raw, offs, sorted);
    lstm_ac_scan<<<1024, 512, 0, stream>>>(fl_pi, fl_vf,
                                           Wih_pi, Whh_pi, bih_pi, bhh_pi,
                                           Wih_vf, Whh_vf, bih_vf, bhh_vf,
                                           ctrs, sorted);
    lstm_ac_heads<<<NROWS / 256, 256, 0, stream>>>(fl_pi, fl_vf, action,
                                                   Wa, ba, Wc, bc, out);
}

// Round 7
// 1749.643 us; speedup vs baseline: 1.2273x; 1.0000x over previous
//
#include <hip/hip_runtime.h>

// LSTM actor-critic forward, round 5 (resubmit — round-6 bench never ran).
// Round-4 lesson: LDS occupancy clamps change the wave budget but NOT the
// scheduler's decision to SINK/REMATERIALIZE the loop-invariant weight loads
// (const __restrict__ loads are "free" to re-issue). Scan stayed VGPR=56,
// feat stayed VGPR=116 (<192 needed) and got slower from lost occupancy.
// Fix this round: pin every weight float with `asm volatile("" : "+v"(x))`
// after loading — the def becomes an opaque asm result that cannot be
// rematerialized or sunk, forcing true VGPR residency.
// 56 KB LDS clamps stay: scan 512t -> 2 blk/CU -> 4 waves/SIMD -> 128-VGPR
// budget; feat 256t -> 2 blk/CU -> 2 waves/SIMD -> 256-VGPR budget.

#define NSEQ  256
#define TT    1024
#define NROWS (NSEQ * TT)     // 262144
#define OBS   128
#define ACTN  16
#define HH    64
#define MAXEP NROWS

#define KEEP(x) asm volatile("" : "+v"(x))

__device__ __forceinline__ float frcp(float x)  { return __builtin_amdgcn_rcpf(x); }
__device__ __forceinline__ float fsigm(float x) { return frcp(1.f + __expf(-x)); }
__device__ __forceinline__ float ftanh(float x) { return 1.f - 2.f * frcp(1.f + __expf(2.f * x)); }

// ---------------------------------------------------------------- K0: zero counters + histogram
__global__ void lstm_ac_zero(int* ctrs, int* hist) {
    const int t = threadIdx.x;
    hist[t] = 0;
    if (t < 8) ctrs[t] = 0;
}

// ---------------------------------------------------------------- K1: episode extraction + length histogram
__global__ void lstm_ac_episodes(const float* __restrict__ ep,
                                 int* __restrict__ ctrs, int* __restrict__ hist,
                                 int2* __restrict__ raw) {
    __shared__ float flags[TT];
    const int s = blockIdx.x;
    for (int i = threadIdx.x; i < TT; i += blockDim.x) flags[i] = ep[(size_t)s * TT + i];
    __syncthreads();
    for (int t0 = threadIdx.x; t0 < TT; t0 += blockDim.x) {
        const bool start = (t0 == 0) || (flags[t0] > 0.5f);
        if (start) {
            int t1 = t0 + 1;
            while (t1 < TT && !(flags[t1] > 0.5f)) t1++;
            const int len = t1 - t0;
            const int slot = atomicAdd(&ctrs[0], 1);
            raw[slot] = make_int2(s * TT + t0, len);
            atomicAdd(&hist[len - 1], 1);
        }
    }
}

// ---------------------------------------------------------------- K2: suffix prefix-sum (descending-length offsets)
__global__ void lstm_ac_prefix(const int* __restrict__ hist, int* __restrict__ offs) {
    __shared__ int a[1024];
    const int tid = threadIdx.x;
    const int h0 = hist[tid];
    a[tid] = h0;
    __syncthreads();
    for (int s = 1; s < 1024; s <<= 1) {
        const int v = (tid + s < 1024) ? a[tid + s] : 0;
        __syncthreads();
        a[tid] += v;
        __syncthreads();
    }
    offs[tid] = a[tid] - h0;   // count of strictly longer episodes
}

// ---------------------------------------------------------------- K3: scatter into length-sorted order
__global__ void lstm_ac_scatter(const int* __restrict__ ctrs, const int2* __restrict__ raw,
                                int* __restrict__ offs, int2* __restrict__ sorted) {
    const int i = blockIdx.x * 256 + threadIdx.x;
    if (i < ctrs[0]) {
        const int2 e = raw[i];
        const int slot = atomicAdd(&offs[e.y - 1], 1);
        sorted[slot] = e;
    }
}

// ---------------------------------------------------------------- K4: MLP features (both branches, one launch)
// blocks [0,2048) -> pi, [2048,4096) -> vf. Lane j owns output feature j;
// W1 row j (128 f32) + W2 row j (64 f32) pinned in VGPRs via KEEP.
__global__ __launch_bounds__(256)
void lstm_ac_feat(
    const float* __restrict__ obs,
    const float* __restrict__ Wp1, const float* __restrict__ bp1,
    const float* __restrict__ Wp2, const float* __restrict__ bp2,
    const float* __restrict__ Wv1, const float* __restrict__ bv1,
    const float* __restrict__ Wv2, const float* __restrict__ bv2,
    float* __restrict__ fl_pi, float* __restrict__ fl_vf) {
    __shared__ float lds_pool[14336];             // 56 KB occupancy clamp
    float (*x_lds)[OBS] = (float (*)[OBS])(lds_pool);          // [4][128]
    float (*l1_lds)[HH] = (float (*)[HH])(lds_pool + 4 * OBS); // [4][64]
    const int tid = threadIdx.x;
    const int w = tid >> 6, j = tid & 63;
    const int half = blockIdx.x >> 11;            // 0 = pi, 1 = vf
    const float* W1 = half ? Wv1 : Wp1;
    const float* b1 = half ? bv1 : bp1;
    const float* W2 = half ? Wv2 : Wp2;
    const float* b2 = half ? bv2 : bp2;
    float* feat = half ? fl_vf : fl_pi;

    float w1r[OBS], w2r[HH];
    {
        const float4* p1 = (const float4*)(W1 + (size_t)j * OBS);
#pragma unroll
        for (int q = 0; q < OBS / 4; q++) {
            float4 v = p1[q];
            w1r[4*q] = v.x; w1r[4*q+1] = v.y; w1r[4*q+2] = v.z; w1r[4*q+3] = v.w;
        }
        const float4* p2 = (const float4*)(W2 + (size_t)j * HH);
#pragma unroll
        for (int q = 0; q < HH / 4; q++) {
            float4 v = p2[q];
            w2r[4*q] = v.x; w2r[4*q+1] = v.y; w2r[4*q+2] = v.z; w2r[4*q+3] = v.w;
        }
#pragma unroll
        for (int q = 0; q < OBS; q++) KEEP(w1r[q]);   // pin: no remat/sink
#pragma unroll
        for (int q = 0; q < HH; q++) KEEP(w2r[q]);
    }
    const float bb1 = b1[j], bb2 = b2[j];
    const int gw = (blockIdx.x & 2047) * 4 + w;   // 2048 blocks * 4 waves per branch

    // register prefetch of the first row (issue-early pattern)
    float xa = obs[(size_t)(gw * 32) * OBS + j];
    float xb = obs[(size_t)(gw * 32) * OBS + HH + j];
    for (int rr = 0; rr < 32; ++rr) {
        const int r = gw * 32 + rr;
        x_lds[w][j]      = xa;
        x_lds[w][HH + j] = xb;
        if (rr + 1 < 32) {                        // issue next row's load now
            xa = obs[(size_t)(r + 1) * OBS + j];
            xb = obs[(size_t)(r + 1) * OBS + HH + j];
        }
        const float4* xv4 = (const float4*)x_lds[w];
        float sa[4] = {0.f, 0.f, 0.f, 0.f};
#pragma unroll
        for (int q = 0; q < OBS / 4; q++) {
            float4 v = xv4[q];
            sa[q & 3] += v.x * w1r[4*q] + v.y * w1r[4*q+1] + v.z * w1r[4*q+2] + v.w * w1r[4*q+3];
        }
        const float l1 = ftanh(bb1 + (sa[0] + sa[1]) + (sa[2] + sa[3]));
        l1_lds[w][j] = l1;
        const float4* lv4 = (const float4*)l1_lds[w];
        float ta[4] = {0.f, 0.f, 0.f, 0.f};
#pragma unroll
        for (int q = 0; q < HH / 4; q++) {
            float4 v = lv4[q];
            ta[q & 3] += v.x * w2r[4*q] + v.y * w2r[4*q+1] + v.z * w2r[4*q+2] + v.w * w2r[4*q+3];
        }
        feat[(size_t)r * HH + j] = ftanh(bb2 + (ta[0] + ta[1]) + (ta[2] + ta[3]));
    }
}

// ---------------------------------------------------------------- K5: batched episode-parallel LSTM scan
// 512 threads = 8 waves; lane l of wave w: gate g = 32w + (l>>1), k-half
// kh = l&1 -> 32+32 weight floats per lane, pinned via KEEP.
__global__ __launch_bounds__(512)
void lstm_ac_scan(
    float* __restrict__ fl_pi, float* __restrict__ fl_vf,
    const float* __restrict__ Wih_pi, const float* __restrict__ Whh_pi,
    const float* __restrict__ bih_pi, const float* __restrict__ bhh_pi,
    const float* __restrict__ Wih_vf, const float* __restrict__ Whh_vf,
    const float* __restrict__ bih_vf, const float* __restrict__ bhh_vf,
    int* __restrict__ ctrs, const int2* __restrict__ sorted) {
    __shared__ float lds_pool[14336];             // 56 KB occupancy clamp
    float (*x_lds)[HH]     = (float (*)[HH])(lds_pool);          // [4][64]
    float (*h_lds)[HH]     = (float (*)[HH])(lds_pool + 256);    // [4][64]
    float (*g_lds)[4 * HH] = (float (*)[4 * HH])(lds_pool + 512);// [4][256]
    __shared__ int task_s;

    const int tid = threadIdx.x;
    const int w   = tid >> 6;               // wave 0..7
    const int l   = tid & 63;
    const int g   = (w << 5) + (l >> 1);    // gate 0..255 (i,f,g,o blocks)
    const int kh  = l & 1;
    const int kbase = kh * 32;
    const bool upd = (w < 4);
    const int b_me = upd ? w : (w - 4);     // episode slot this wave serves in phase B
    const int j = l;
    const bool is_tanh_gate = ((w >> 1) == 2);

    const int cnt = ctrs[0];
    const int G = (cnt + 3) >> 2;
    const int ntasks = 2 * G;

    int cur = -1;
    float wih[32], whh[32];
    float bg = 0.f;
    float* fl = fl_pi;
    float c_reg = 0.f;

    for (;;) {
        __syncthreads();
        if (tid == 0) task_s = atomicAdd(&ctrs[1], 1);
        __syncthreads();
        const int task = task_s;
        if (task >= ntasks) break;
        const int lstm = (task >= G) ? 1 : 0;
        const int gq = lstm ? (task - G) : task;
        if (lstm != cur) {                  // task ids increase per block: <=1 switch
            cur = lstm;
            const float* Wih = lstm ? Wih_vf : Wih_pi;
            const float* Whh = lstm ? Whh_vf : Whh_pi;
            const float* bih = lstm ? bih_vf : bih_pi;
            const float* bhh = lstm ? bhh_vf : bhh_pi;
            fl = lstm ? fl_vf : fl_pi;
            const float4* p1 = (const float4*)(Wih + (size_t)g * HH + kbase);
            const float4* p2 = (const float4*)(Whh + (size_t)g * HH + kbase);
#pragma unroll
            for (int q = 0; q < 8; q++) {
                float4 a = p1[q];
                wih[4*q+0] = a.x; wih[4*q+1] = a.y; wih[4*q+2] = a.z; wih[4*q+3] = a.w;
                float4 b = p2[q];
                whh[4*q+0] = b.x; whh[4*q+1] = b.y; whh[4*q+2] = b.z; whh[4*q+3] = b.w;
            }
            bg = (kh == 0) ? (bih[g] + bhh[g]) : 0.f;
#pragma unroll
            for (int q = 0; q < 32; q++) { KEEP(wih[q]); KEEP(whh[q]); }
            KEEP(bg);                       // pin: no remat/sink into the t-loop
        }

        // named scalars (no runtime-indexed locals -> no scratch)
        const int base = gq * 4;
        int2 e;
        e = (base + 0 < cnt) ? sorted[base + 0] : make_int2(0, 0); const int r00 = e.x, ln0 = e.y;
        e = (base + 1 < cnt) ? sorted[base + 1] : make_int2(0, 0); const int r01 = e.x, ln1 = e.y;
        e = (base + 2 < cnt) ? sorted[base + 2] : make_int2(0, 0); const int r02 = e.x, ln2 = e.y;
        e = (base + 3 < cnt) ? sorted[base + 3] : make_int2(0, 0); const int r03 = e.x, ln3 = e.y;
        const int r0_me = (b_me == 0) ? r00 : (b_me == 1) ? r01 : (b_me == 2) ? r02 : r03;
        const int ln_me = (b_me == 0) ? ln0 : (b_me == 1) ? ln1 : (b_me == 2) ? ln2 : ln3;
        const int maxlen = ln0;             // descending sort -> slot 0 longest

        if (upd) { h_lds[b_me][j] = 0.f; c_reg = 0.f; }
        else if (ln_me > 0) x_lds[b_me][j] = fl[(size_t)r0_me * HH + j];
        __syncthreads();

        for (int t = 0; t < maxlen; ++t) {
            // issue next x-row load early; consumed in phase B (latency hides
            // under the gate FMAs)
            float xnext = 0.f;
            if (!upd) {
                const int tn = t + 1;
                const int rr = (tn < ln_me) ? (r0_me + tn) : r0_me;
                xnext = fl[(size_t)rr * HH + j];
            }
            // phase A: gates for all active episodes (wave-uniform predicates)
#define GATE_B(B, LNB)                                                          \
            if (t < LNB) {                                                      \
                const float4* xv = (const float4*)&x_lds[B][kbase];             \
                const float4* hv = (const float4*)&h_lds[B][kbase];             \
                float a0 = bg, a1 = 0.f, a2 = 0.f, a3 = 0.f;                    \
                _Pragma("unroll")                                               \
                for (int q = 0; q < 8; q++) {                                   \
                    const float4 x4 = xv[q];                                    \
                    const float4 h4 = hv[q];                                    \
                    a0 += x4.x * wih[4*q+0] + h4.x * whh[4*q+0];                \
                    a1 += x4.y * wih[4*q+1] + h4.y * whh[4*q+1];                \
                    a2 += x4.z * wih[4*q+2] + h4.z * whh[4*q+2];                \
                    a3 += x4.w * wih[4*q+3] + h4.w * whh[4*q+3];                \
                }                                                               \
                float part = (a0 + a1) + (a2 + a3);                             \
                part += __shfl_xor(part, 1, 64);                                \
                g_lds[B][g] = is_tanh_gate ? ftanh(part) : fsigm(part);         \
            }
            GATE_B(0, ln0)
            GATE_B(1, ln1)
            GATE_B(2, ln2)
            GATE_B(3, ln3)
#undef GATE_B
            __syncthreads();
            // phase B
            if (upd) {
                if (t < ln_me) {
                    const float gi = g_lds[b_me][j];
                    const float gf = g_lds[b_me][HH + j];
                    const float gg = g_lds[b_me][2 * HH + j];
                    const float go = g_lds[b_me][3 * HH + j];
                    c_reg = gf * c_reg + gi * gg;
                    const float h = go * ftanh(c_reg);
                    h_lds[b_me][j] = h;
                    fl[(size_t)(r0_me + t) * HH + j] = h;  // feat row already consumed
                }
            } else {
                if (t + 1 < ln_me) x_lds[b_me][j] = xnext;
            }
            __syncthreads();
        }
    }
}

// ---------------------------------------------------------------- K6: policy/value heads
__global__ __launch_bounds__(256)
void lstm_ac_heads(
    const float* __restrict__ lat_pi, const float* __restrict__ lat_vf,
    const int* __restrict__ action,
    const float* __restrict__ Wa, const float* __restrict__ ba,
    const float* __restrict__ Wc, const float* __restrict__ bc,
    float* __restrict__ out) {
    const int r = blockIdx.x * 256 + threadIdx.x;
    float4 lp[16];
    const float4* pp = (const float4*)(lat_pi + (size_t)r * HH);
#pragma unroll
    for (int q = 0; q < 16; q++) lp[q] = pp[q];

    float logits[ACTN];
#pragma unroll
    for (int a = 0; a < ACTN; a++) {
        const float4* wp = (const float4*)(Wa + (size_t)a * HH);  // uniform -> s_loads
        float s0 = 0.f, s1 = 0.f, s2 = 0.f, s3 = 0.f;
#pragma unroll
        for (int q = 0; q < 16; q++) {
            const float4 wv = wp[q];
            s0 += lp[q].x * wv.x; s1 += lp[q].y * wv.y;
            s2 += lp[q].z * wv.z; s3 += lp[q].w * wv.w;
        }
        logits[a] = ba[a] + (s0 + s1) + (s2 + s3);
    }
    float m = logits[0];
#pragma unroll
    for (int a = 1; a < ACTN; a++) m = fmaxf(m, logits[a]);
    float s0 = 0.f, s1 = 0.f;
#pragma unroll
    for (int a = 0; a < ACTN; a++) {
        const float e = __expf(logits[a] - m);
        s0 += e;
        s1 += e * logits[a];
    }
    const float lse = m + __logf(s0);
    const int act = action[r];
    float la = logits[0];
#pragma unroll
    for (int a = 1; a < ACTN; a++) la = (act == a) ? logits[a] : la;
    out[r] = la - lse;
    out[NROWS + r] = lse - s1 * frcp(s0);

    const float4* pv = (const float4*)(lat_vf + (size_t)r * HH);
    const float4* wc4 = (const float4*)Wc;
    float t0 = 0.f, t1 = 0.f, t2 = 0.f, t3 = 0.f;
#pragma unroll
    for (int q = 0; q < 16; q++) {
        const float4 v = pv[q];
        const float4 wv = wc4[q];
        t0 += v.x * wv.x; t1 += v.y * wv.y; t2 += v.z * wv.z; t3 += v.w * wv.w;
    }
    out[2 * (size_t)NROWS + r] = bc[0] + (t0 + t1) + (t2 + t3);
}

// ---------------------------------------------------------------- launch
extern "C" void kernel_launch(void* const* d_in, const int* in_sizes, int n_in,
                              void* d_out, int out_size, void* d_ws, size_t ws_size,
                              hipStream_t stream) {
    const float* obs    = (const float*)d_in[0];
    const int*   action = (const int*)d_in[1];
    const float* epst   = (const float*)d_in[2];
    const float* Wp1 = (const float*)d_in[7];
    const float* bp1 = (const float*)d_in[8];
    const float* Wp2 = (const float*)d_in[9];
    const float* bp2 = (const float*)d_in[10];
    const float* Wv1 = (const float*)d_in[11];
    const float* bv1 = (const float*)d_in[12];
    const float* Wv2 = (const float*)d_in[13];
    const float* bv2 = (const float*)d_in[14];
    const float* Wih_pi = (const float*)d_in[15];
    const float* Whh_pi = (const float*)d_in[16];
    const float* bih_pi = (const float*)d_in[17];
    const float* bhh_pi = (const float*)d_in[18];
    const float* Wih_vf = (const float*)d_in[19];
    const float* Whh_vf = (const float*)d_in[20];
    const float* bih_vf = (const float*)d_in[21];
    const float* bhh_vf = (const float*)d_in[22];
    const float* Wa = (const float*)d_in[23];
    const float* ba = (const float*)d_in[24];
    const float* Wc = (const float*)d_in[25];
    const float* bc = (const float*)d_in[26];
    float* out = (float*)d_out;

    char* ws = (char*)d_ws;
    int*  ctrs   = (int*)ws;
    int*  hist   = (int*)(ws + 32);
    int*  offs   = (int*)(ws + 32 + 4096);
    int2* raw    = (int2*)(ws + 32 + 8192);
    int2* sorted = raw + MAXEP;
    float* fl_pi = (float*)((char*)(sorted + MAXEP));
    float* fl_vf = fl_pi + (size_t)NROWS * HH;

    lstm_ac_zero<<<1, 1024, 0, stream>>>(ctrs, hist);
    lstm_ac_episodes<<<NSEQ, 256, 0, stream>>>(epst, ctrs, hist, raw);
    lstm_ac_feat<<<4096, 256, 0, stream>>>(obs, Wp1, bp1, Wp2, bp2,
                                           Wv1, bv1, Wv2, bv2, fl_pi, fl_vf);
    lstm_ac_prefix<<<1, 1024, 0, stream>>>(hist, offs);
    lstm_ac_scatter<<<1024, 256, 0, stream>>>(ctrs, raw, offs, sorted);
    lstm_ac_scan<<<1024, 512, 0, stream>>>(fl_pi, fl_vf,
                                           Wih_pi, Whh_pi, bih_pi, bhh_pi,
                                           Wih_vf, Whh_vf, bih_vf, bhh_vf,
                                           ctrs, sorted);
    lstm_ac_heads<<<NROWS / 256, 256, 0, stream>>>(fl_pi, fl_vf, action,
                                                   Wa, ba, Wc, bc, out);
}